// Round 11
// baseline (110.494 us; speedup 1.0000x reference)
//
#include <hip/hip_runtime.h>
#include <hip/hip_fp16.h>

#define D_FEAT 64

// Fused prep kernel: [0, rb) blocks repack feat f32->f16; [rb, rb+eb) build
// row_ptr via edge-parallel boundary scatter (edge_dst sorted).
__global__ __launch_bounds__(256) void prep_kernel(
    const float* __restrict__ feat, uint2* __restrict__ f16,
    const int* __restrict__ edge_dst, int* __restrict__ rp,
    int n_vec4, int n_edges, int n_nodes, int rb) {
  if ((int)blockIdx.x < rb) {
    const int i = blockIdx.x * blockDim.x + threadIdx.x;
    if (i >= n_vec4) return;
    const float4 v = ((const float4*)feat)[i];
    const __half2 h0 = __float22half2_rn(make_float2(v.x, v.y));
    const __half2 h1 = __float22half2_rn(make_float2(v.z, v.w));
    uint2 o;
    o.x = *(const unsigned int*)&h0;
    o.y = *(const unsigned int*)&h1;
    f16[i] = o;
  } else {
    const int e = (blockIdx.x - rb) * blockDim.x + threadIdx.x;
    if (e > n_edges) return;
    const int d0 = (e == 0) ? -1 : edge_dst[e - 1];
    const int d1 = (e == n_edges) ? n_nodes : edge_dst[e];
    for (int v = d0 + 1; v <= d1; ++v) rp[v] = e;
  }
}

// Gather: one wave per destination node, fp16 feat rows (128B).
// lane = 8*slot + part: 8 edge slots x 8 lanes; one dwordx4 per lane = 16B
// of its slot's row -> one edge = one coalesced 128B request.
//
// L2-warm prefix: the gather's FETCH sits at the per-XCD compulsory floor
// (each XCD pulls all of feat16 once), but as RANDOM 128B fills (~2.3TB/s).
// The first WARM_SLICES block-seqs per XCD (xcd = blockIdx&7, round-robin
// heuristic, perf-only) linearly stream one 16KB slice of feat16 each, so
// the compulsory fills happen at streaming rate and gathers hit L2.
__global__ __launch_bounds__(256) void gcn_gather_f16(
    const uint4* __restrict__ feat16,   // [n_nodes*8] 16B chunks
    const float* __restrict__ ew,
    const int* __restrict__ esrc,
    const int* __restrict__ rp,
    float* __restrict__ out, int n_nodes) {
  // ---- L2 warm prefix (XCD-aware) ----
  const int total16 = n_nodes * 8;                  // 16B chunks in feat16
  const int warm_slices = (total16 + 1023) / 1024;  // 16KB slices (~400)
  const int xcd_seq = blockIdx.x >> 3;              // per-XCD block sequence
  if (xcd_seq < warm_slices) {
    const int s0 = xcd_seq * 1024;
#pragma unroll
    for (int t = 0; t < 4; ++t) {
      const int idx = s0 + t * 256 + threadIdx.x;
      if (idx < total16) {
        uint4 q = feat16[idx];
        asm volatile("" :: "v"(q.x), "v"(q.y), "v"(q.z), "v"(q.w));
      }
    }
  }

  const int wave = (blockIdx.x * blockDim.x + threadIdx.x) >> 6;
  const int lane = threadIdx.x & 63;
  if (wave >= n_nodes) return;
  const int slot = lane >> 3;   // edge slot 0..7
  const int part = lane & 7;    // 16B chunk within the 128B row

  const int e0 = rp[wave];
  const int e1 = rp[wave + 1];

  float a0 = 0.f, a1 = 0.f, a2 = 0.f, a3 = 0.f;
  float a4 = 0.f, a5 = 0.f, a6 = 0.f, a7 = 0.f;

  for (int base = e0; base < e1; base += 64) {
    const int n = min(64, e1 - base);
    int   s = 0;
    float w = 0.0f;
    if (lane < n) {
      s = esrc[base + lane];
      w = ew[base + lane];   // padded slots carry w=0 -> contribute zero
    }
#pragma unroll
    for (int r = 0; r < 8; ++r) {
      const int   sk = __shfl(s, r * 8 + slot);
      const float wk = __shfl(w, r * 8 + slot);
      const uint4 q  = feat16[(size_t)sk * 8 + part];
      const float2 f0 = __half22float2(*(const __half2*)&q.x);
      const float2 f1 = __half22float2(*(const __half2*)&q.y);
      const float2 f2 = __half22float2(*(const __half2*)&q.z);
      const float2 f3 = __half22float2(*(const __half2*)&q.w);
      a0 = fmaf(f0.x, wk, a0); a1 = fmaf(f0.y, wk, a1);
      a2 = fmaf(f1.x, wk, a2); a3 = fmaf(f1.y, wk, a3);
      a4 = fmaf(f2.x, wk, a4); a5 = fmaf(f2.y, wk, a5);
      a6 = fmaf(f3.x, wk, a6); a7 = fmaf(f3.y, wk, a7);
    }
  }

  // Reduce the 8 slot-partials (lane bits 3,4,5); part stays fixed.
#pragma unroll
  for (int m = 8; m <= 32; m <<= 1) {
    a0 += __shfl_xor(a0, m); a1 += __shfl_xor(a1, m);
    a2 += __shfl_xor(a2, m); a3 += __shfl_xor(a3, m);
    a4 += __shfl_xor(a4, m); a5 += __shfl_xor(a5, m);
    a6 += __shfl_xor(a6, m); a7 += __shfl_xor(a7, m);
  }

  if (slot == 0) {
    float4* orow = (float4*)(out + (size_t)wave * D_FEAT);
    orow[part * 2]     = make_float4(a0, a1, a2, a3);
    orow[part * 2 + 1] = make_float4(a4, a5, a6, a7);
  }
}

extern "C" void kernel_launch(void* const* d_in, const int* in_sizes, int n_in,
                              void* d_out, int out_size, void* d_ws, size_t ws_size,
                              hipStream_t stream) {
  const float* feat        = (const float*)d_in[0];
  const float* edge_weight = (const float*)d_in[1];
  const int*   edge_src    = (const int*)d_in[2];
  const int*   edge_dst    = (const int*)d_in[3];
  float* out = (float*)d_out;

  const int n_edges = in_sizes[1];            // E = 1,250,000
  const int n_nodes = out_size / D_FEAT;      // N = 50,000

  int*   rp  = (int*)d_ws;                             // (N+1) ints
  uint2* f16 = (uint2*)((char*)d_ws + (1 << 20));      // 6.4MB fp16 feat

  const int n_vec4 = n_nodes * (D_FEAT / 4);  // 800K float4s
  const int rb = (n_vec4 + 255) / 256;
  const int eb = (n_edges + 1 + 255) / 256;
  prep_kernel<<<rb + eb, 256, 0, stream>>>(
      feat, f16, edge_dst, rp, n_vec4, n_edges, n_nodes, rb);

  const long total_threads = (long)n_nodes * 64;
  gcn_gather_f16<<<(int)((total_threads + 255) / 256), 256, 0, stream>>>(
      (const uint4*)f16, edge_weight, edge_src, rp, out, n_nodes);
}